// Round 1
// baseline (176.666 us; speedup 1.0000x reference)
//
#include <hip/hip_runtime.h>
#include <math.h>

#define KNBR 16
#define DIM 64
#define NREL 32

__global__ __launch_bounds__(64) void kgnnls_kernel(
    const int* __restrict__ u_ids, const int* __restrict__ i_ids,
    const int* __restrict__ adj_entity, const int* __restrict__ adj_relation,
    const float* __restrict__ user_emb, const float* __restrict__ entity_emb,
    const float* __restrict__ relation_emb,
    const float* __restrict__ W0, const float* __restrict__ b0,
    const float* __restrict__ W1, const float* __restrict__ b1,
    float* __restrict__ out)
{
    const int b = blockIdx.x;
    const int lane = threadIdx.x;  // 0..63, dual role: dim index d / output index e

    __shared__ float xbuf[17][DIM];
    __shared__ float uebuf[DIM];

    const int u  = u_ids[b];
    const int i0 = i_ids[b];

    const float ue = user_emb[u * DIM + lane];
    uebuf[lane] = ue;

    // W0 column per lane: Wc0[j] = W0[lane][j]  (lane e owns output row e)
    float Wc0[DIM];
    {
        const float4* wrow = (const float4*)(W0 + lane * DIM);
        #pragma unroll
        for (int q = 0; q < 16; ++q) {
            float4 w = wrow[q];
            Wc0[4*q+0] = w.x; Wc0[4*q+1] = w.y; Wc0[4*q+2] = w.z; Wc0[4*q+3] = w.w;
        }
    }
    const float bias0 = b0[lane];

    __syncthreads();

    // s[r] at lane r (r < 33): s = (1/64) * dot(ue, relation_emb[r])
    float s_val = 0.f;
    if (lane < NREL + 1) {
        const float4* rrow = (const float4*)(relation_emb + lane * DIM);
        const float4* ub   = (const float4*)uebuf;
        float acc = 0.f;
        #pragma unroll
        for (int q = 0; q < 16; ++q) {
            float4 r4 = rrow[q];
            float4 u4 = ub[q];   // same address across lanes -> LDS broadcast
            acc += r4.x*u4.x + r4.y*u4.y + r4.z*u4.z + r4.w*u4.w;
        }
        s_val = acc * (1.0f / DIM);
    }

    // hop-0 neighbor/relation indices at lanes 0..15
    int e1k = 0, r0k = 0;
    if (lane < KNBR) {
        e1k = adj_entity [i0 * KNBR + lane];
        r0k = adj_relation[i0 * KNBR + lane];
    }

    // softmax over k (16) for hop-0 scores, valid at lanes 0..15
    float sc0 = __shfl(s_val, r0k);
    float m0 = sc0;
    m0 = fmaxf(m0, __shfl_xor(m0, 1));
    m0 = fmaxf(m0, __shfl_xor(m0, 2));
    m0 = fmaxf(m0, __shfl_xor(m0, 4));
    m0 = fmaxf(m0, __shfl_xor(m0, 8));
    float ex0 = __expf(sc0 - m0);
    float z0 = ex0;
    z0 += __shfl_xor(z0, 1);
    z0 += __shfl_xor(z0, 2);
    z0 += __shfl_xor(z0, 4);
    z0 += __shfl_xor(z0, 8);
    const float attn0 = ex0 / z0;     // lanes 0..15 hold attn0[k]

    // hop-1: lane handles k = lane>>2, j in [4*(lane&3), +4)
    const int kk = lane >> 2;
    const int jb = (lane & 3) * 4;
    const int ek = __shfl(e1k, kk);
    const int4 e2i = *(const int4*)(adj_entity  + ek * KNBR + jb);
    const int4 r2i = *(const int4*)(adj_relation + ek * KNBR + jb);
    int e2idx[4] = { e2i.x, e2i.y, e2i.z, e2i.w };

    float sc1[4];
    sc1[0] = __shfl(s_val, r2i.x);
    sc1[1] = __shfl(s_val, r2i.y);
    sc1[2] = __shfl(s_val, r2i.z);
    sc1[3] = __shfl(s_val, r2i.w);

    // softmax over the 16 j's: intra-lane over 4 + xor over lanes {1,2} (4-lane aligned groups)
    float m1 = fmaxf(fmaxf(sc1[0], sc1[1]), fmaxf(sc1[2], sc1[3]));
    m1 = fmaxf(m1, __shfl_xor(m1, 1));
    m1 = fmaxf(m1, __shfl_xor(m1, 2));
    float a1[4];
    float z1 = 0.f;
    #pragma unroll
    for (int t = 0; t < 4; ++t) { a1[t] = __expf(sc1[t] - m1); z1 += a1[t]; }
    z1 += __shfl_xor(z1, 1);
    z1 += __shfl_xor(z1, 2);
    const float inv_z1 = 1.0f / z1;
    #pragma unroll
    for (int t = 0; t < 4; ++t) a1[t] *= inv_z1;

    // Aggregation: build x rows for layer-0 matmul. Lane = d.
    float agg0 = 0.f;
    for (int k = 0; k < KNBR; ++k) {
        const int   ei = __shfl(e1k, k);
        const float v1 = entity_emb[ei * DIM + lane];   // ev1[k][d]
        const float a0 = __shfl(attn0, k);
        agg0 += a0 * v1;

        float acc = 0.f;
        #pragma unroll
        for (int j = 0; j < KNBR; ++j) {
            const int src = 4 * k + (j >> 2);           // lane holding (k, j)
            const float a  = __shfl(a1[j & 3], src);
            const int   ei2 = __shfl(e2idx[j & 3], src);
            const float v2 = entity_emb[ei2 * DIM + lane];
            acc += a * v2;
        }
        xbuf[1 + k][lane] = v1 + acc * (1.0f / KNBR);   // x1[k] = ev1[k] + agg1[k]
    }
    {
        const float ev0 = entity_emb[i0 * DIM + lane];
        xbuf[0][lane] = ev0 + agg0 * (1.0f / KNBR);     // x0 = ev0 + agg0
    }
    __syncthreads();

    // Layer-0 matmul: h[r][e] = relu( sum_d x[r][d] * W0[e][d] + b0[e] ), 17 rows
    float h[17];
    #pragma unroll
    for (int r = 0; r < 17; ++r) {
        const float4* xb = (const float4*)xbuf[r];
        float acc = bias0;
        #pragma unroll
        for (int q = 0; q < 16; ++q) {
            float4 xv = xb[q];  // broadcast read
            acc += xv.x * Wc0[4*q+0] + xv.y * Wc0[4*q+1]
                 + xv.z * Wc0[4*q+2] + xv.w * Wc0[4*q+3];
        }
        h[r] = fmaxf(acc, 0.f);
    }

    // Layer-1: agg over h1 with the SAME attn0, then tanh((h0+agg) @ W1^T + b1)
    float aggL = 0.f;
    #pragma unroll
    for (int k = 0; k < KNBR; ++k) {
        const float a0 = __shfl(attn0, k);
        aggL += a0 * h[1 + k];
    }
    const float xL = h[0] + aggL * (1.0f / KNBR);
    __syncthreads();
    xbuf[0][lane] = xL;
    __syncthreads();

    float Wc1[DIM];
    {
        const float4* wrow = (const float4*)(W1 + lane * DIM);
        #pragma unroll
        for (int q = 0; q < 16; ++q) {
            float4 w = wrow[q];
            Wc1[4*q+0] = w.x; Wc1[4*q+1] = w.y; Wc1[4*q+2] = w.z; Wc1[4*q+3] = w.w;
        }
    }
    float acc1 = b1[lane];
    {
        const float4* xb = (const float4*)xbuf[0];
        #pragma unroll
        for (int q = 0; q < 16; ++q) {
            float4 xv = xb[q];
            acc1 += xv.x * Wc1[4*q+0] + xv.y * Wc1[4*q+1]
                  + xv.z * Wc1[4*q+2] + xv.w * Wc1[4*q+3];
        }
    }
    const float item = tanhf(acc1);

    // score = sigmoid( sum_d ue[d] * item[d] )
    float p = ue * item;
    #pragma unroll
    for (int m = 1; m < 64; m <<= 1) p += __shfl_xor(p, m);
    if (lane == 0) out[b] = 1.0f / (1.0f + __expf(-p));
}

extern "C" void kernel_launch(void* const* d_in, const int* in_sizes, int n_in,
                              void* d_out, int out_size, void* d_ws, size_t ws_size,
                              hipStream_t stream) {
    const int*   u_ids        = (const int*)  d_in[0];
    const int*   i_ids        = (const int*)  d_in[1];
    const int*   adj_entity   = (const int*)  d_in[2];
    const int*   adj_relation = (const int*)  d_in[3];
    const float* user_emb     = (const float*)d_in[4];
    const float* entity_emb   = (const float*)d_in[5];
    const float* relation_emb = (const float*)d_in[6];
    const float* W0           = (const float*)d_in[7];
    const float* b0           = (const float*)d_in[8];
    const float* W1           = (const float*)d_in[9];
    const float* b1           = (const float*)d_in[10];
    float* out = (float*)d_out;

    const int B = in_sizes[0];
    hipLaunchKernelGGL(kgnnls_kernel, dim3(B), dim3(64), 0, stream,
        u_ids, i_ids, adj_entity, adj_relation, user_emb, entity_emb,
        relation_emb, W0, b0, W1, b1, out);
}

// Round 2
// 159.449 us; speedup vs baseline: 1.1080x; 1.1080x over previous
//
#include <hip/hip_runtime.h>
#include <math.h>

#define KNBR 16
#define DIM 64
#define NREL 32
#define WPB 4   // waves (batch elements) per 256-thread block

__global__ __launch_bounds__(256, 7) void kgnnls_kernel(
    const int* __restrict__ u_ids, const int* __restrict__ i_ids,
    const int* __restrict__ adj_entity, const int* __restrict__ adj_relation,
    const float* __restrict__ user_emb, const float* __restrict__ entity_emb,
    const float* __restrict__ relation_emb,
    const float* __restrict__ W0, const float* __restrict__ b0,
    const float* __restrict__ W1, const float* __restrict__ b1,
    float* __restrict__ out, int B)
{
    const int tid  = threadIdx.x;
    const int wave = tid >> 6;
    const int lane = tid & 63;          // dual role: dim index d / output index e
    int b = blockIdx.x * WPB + wave;
    if (b >= B) b = B - 1;              // duplicate work, benign duplicate write

    __shared__ float xbuf[WPB][17][DIM];
    __shared__ float uebuf[WPB][DIM];

    const int u  = u_ids[b];
    const int i0 = i_ids[b];

    const float ue = user_emb[u * DIM + lane];
    uebuf[wave][lane] = ue;

    const float bias0 = b0[lane];

    __syncthreads();

    // s[r] at lane r (r < 33): s = (1/64) * dot(ue, relation_emb[r])
    float s_val = 0.f;
    if (lane < NREL + 1) {
        const float4* rrow = (const float4*)(relation_emb + lane * DIM);
        const float4* ub   = (const float4*)uebuf[wave];
        float acc = 0.f;
        #pragma unroll
        for (int q = 0; q < 16; ++q) {
            float4 r4 = rrow[q];
            float4 u4 = ub[q];   // same address across lanes -> LDS broadcast
            acc += r4.x*u4.x + r4.y*u4.y + r4.z*u4.z + r4.w*u4.w;
        }
        s_val = acc * (1.0f / DIM);
    }

    // hop-0 neighbor/relation indices at lanes 0..15
    int e1k = 0, r0k = 0;
    if (lane < KNBR) {
        e1k = adj_entity [i0 * KNBR + lane];
        r0k = adj_relation[i0 * KNBR + lane];
    }

    // softmax over k (16) for hop-0 scores, valid at lanes 0..15
    float sc0 = __shfl(s_val, r0k);
    float m0 = sc0;
    m0 = fmaxf(m0, __shfl_xor(m0, 1));
    m0 = fmaxf(m0, __shfl_xor(m0, 2));
    m0 = fmaxf(m0, __shfl_xor(m0, 4));
    m0 = fmaxf(m0, __shfl_xor(m0, 8));
    float ex0 = __expf(sc0 - m0);
    float z0 = ex0;
    z0 += __shfl_xor(z0, 1);
    z0 += __shfl_xor(z0, 2);
    z0 += __shfl_xor(z0, 4);
    z0 += __shfl_xor(z0, 8);
    const float attn0 = ex0 / z0;     // lanes 0..15 hold attn0[k]

    // hop-1: lane handles k = lane>>2, j in [4*(lane&3), +4)
    const int kk = lane >> 2;
    const int jb = (lane & 3) * 4;
    const int ek = __shfl(e1k, kk);
    const int4 e2i = *(const int4*)(adj_entity  + ek * KNBR + jb);
    const int4 r2i = *(const int4*)(adj_relation + ek * KNBR + jb);
    int e2idx[4] = { e2i.x, e2i.y, e2i.z, e2i.w };

    float sc1[4];
    sc1[0] = __shfl(s_val, r2i.x);
    sc1[1] = __shfl(s_val, r2i.y);
    sc1[2] = __shfl(s_val, r2i.z);
    sc1[3] = __shfl(s_val, r2i.w);

    // softmax over the 16 j's: intra-lane over 4 + xor over lanes {1,2}
    float m1 = fmaxf(fmaxf(sc1[0], sc1[1]), fmaxf(sc1[2], sc1[3]));
    m1 = fmaxf(m1, __shfl_xor(m1, 1));
    m1 = fmaxf(m1, __shfl_xor(m1, 2));
    float a1[4];
    float z1 = 0.f;
    #pragma unroll
    for (int t = 0; t < 4; ++t) { a1[t] = __expf(sc1[t] - m1); z1 += a1[t]; }
    z1 += __shfl_xor(z1, 1);
    z1 += __shfl_xor(z1, 2);
    const float inv_z1 = 1.0f / z1;
    #pragma unroll
    for (int t = 0; t < 4; ++t) a1[t] *= inv_z1;

    // Aggregation: build x rows for layer-0 matmul. Lane = d.
    float agg0 = 0.f;
    for (int k = 0; k < KNBR; ++k) {
        const int   ei = __shfl(e1k, k);
        const float v1 = entity_emb[ei * DIM + lane];   // ev1[k][d]
        const float a0 = __shfl(attn0, k);
        agg0 += a0 * v1;

        float acc = 0.f;
        #pragma unroll
        for (int j = 0; j < KNBR; ++j) {
            const int src = 4 * k + (j >> 2);           // lane holding (k, j)
            const float a  = __shfl(a1[j & 3], src);
            const int   ei2 = __shfl(e2idx[j & 3], src);
            const float v2 = entity_emb[ei2 * DIM + lane];
            acc += a * v2;
        }
        xbuf[wave][1 + k][lane] = v1 + acc * (1.0f / KNBR);  // x1[k] = ev1[k] + agg1[k]
    }
    {
        const float ev0 = entity_emb[i0 * DIM + lane];
        xbuf[wave][0][lane] = ev0 + agg0 * (1.0f / KNBR);    // x0 = ev0 + agg0
    }
    __syncthreads();

    // Layer-0 matmul: h[r][e] = relu( sum_d x[r][d] * W0[e][d] + b0[e] ), 17 rows
    float h[17];
    {
        #pragma unroll
        for (int r = 0; r < 17; ++r) h[r] = bias0;
        const float4* wrow = (const float4*)(W0 + lane * DIM);
        #pragma unroll
        for (int q = 0; q < 16; ++q) {
            float4 w = wrow[q];   // L1-resident after first block touches it
            #pragma unroll
            for (int r = 0; r < 17; ++r) {
                float4 xv = ((const float4*)xbuf[wave][r])[q];  // broadcast read
                h[r] += xv.x * w.x + xv.y * w.y + xv.z * w.z + xv.w * w.w;
            }
        }
        #pragma unroll
        for (int r = 0; r < 17; ++r) h[r] = fmaxf(h[r], 0.f);
    }

    // Layer-1: agg over h1 with the SAME attn0, then tanh((h0+agg) @ W1^T + b1)
    float aggL = 0.f;
    #pragma unroll
    for (int k = 0; k < KNBR; ++k) {
        const float a0 = __shfl(attn0, k);
        aggL += a0 * h[1 + k];
    }
    const float xL = h[0] + aggL * (1.0f / KNBR);
    __syncthreads();
    xbuf[wave][0][lane] = xL;
    __syncthreads();

    float acc1 = b1[lane];
    {
        const float4* wrow = (const float4*)(W1 + lane * DIM);
        const float4* xb   = (const float4*)xbuf[wave][0];
        #pragma unroll
        for (int q = 0; q < 16; ++q) {
            float4 w  = wrow[q];
            float4 xv = xb[q];
            acc1 += xv.x * w.x + xv.y * w.y + xv.z * w.z + xv.w * w.w;
        }
    }
    const float item = tanhf(acc1);

    // score = sigmoid( sum_d ue[d] * item[d] )
    float p = ue * item;
    #pragma unroll
    for (int m = 1; m < 64; m <<= 1) p += __shfl_xor(p, m);
    if (lane == 0) out[b] = 1.0f / (1.0f + __expf(-p));
}

extern "C" void kernel_launch(void* const* d_in, const int* in_sizes, int n_in,
                              void* d_out, int out_size, void* d_ws, size_t ws_size,
                              hipStream_t stream) {
    const int*   u_ids        = (const int*)  d_in[0];
    const int*   i_ids        = (const int*)  d_in[1];
    const int*   adj_entity   = (const int*)  d_in[2];
    const int*   adj_relation = (const int*)  d_in[3];
    const float* user_emb     = (const float*)d_in[4];
    const float* entity_emb   = (const float*)d_in[5];
    const float* relation_emb = (const float*)d_in[6];
    const float* W0           = (const float*)d_in[7];
    const float* b0           = (const float*)d_in[8];
    const float* W1           = (const float*)d_in[9];
    const float* b1           = (const float*)d_in[10];
    float* out = (float*)d_out;

    const int B = in_sizes[0];
    const int grid = (B + WPB - 1) / WPB;
    hipLaunchKernelGGL(kgnnls_kernel, dim3(grid), dim3(64 * WPB), 0, stream,
        u_ids, i_ids, adj_entity, adj_relation, user_emb, entity_emb,
        relation_emb, W0, b0, W1, b1, out, B);
}